// Round 1
// baseline (60.111 us; speedup 1.0000x reference)
//
#include <hip/hip_runtime.h>

#define NB   128   // images
#define NP   512   // pairs per image
#define NC   150   // foreground classes
#define ND   1024  // PATH_DIM

// Kernel A: for image i, build multi-hot in LDS, compute y[d] = b[d] + sum_c flag[c]*W[d*150+c]
// and write it into out row (i*NP + 0)  -- i.e. row 0 of each image's block.
// grid.x = 128*4, block = 256: bid>>2 = image, bid&3 = which 256-chunk of D.
__global__ __launch_bounds__(256) void compute_y_kernel(const int* __restrict__ preds,
                                                        const float* __restrict__ W,
                                                        const float* __restrict__ bias,
                                                        float* __restrict__ out) {
    __shared__ float sflag[NC];
    const unsigned bid  = blockIdx.x;
    const unsigned img  = bid >> 2;
    const unsigned dblk = bid & 3;
    const unsigned t    = threadIdx.x;

    if (t < NC) sflag[t] = 0.0f;
    __syncthreads();

    const int* pp = preds + (size_t)img * NP;
    #pragma unroll
    for (int p = (int)t; p < NP; p += 256) {
        int c = pp[p] - 1;          // classes 1..150 -> 0..149
        sflag[c] = 1.0f;            // idempotent; same-value races are benign
    }
    __syncthreads();

    const int d = (int)(dblk * 256 + t);
    const float* w = W + (size_t)d * NC;
    float y = bias[d];
    #pragma unroll
    for (int c = 0; c < NC; ++c) {
        y += sflag[c] * w[c];       // sflag broadcast (no bank conflict); W is L2-resident
    }
    out[(size_t)img * NP * ND + (size_t)d] = y;
}

// Kernel B: broadcast row 0 of each image to its remaining 511 rows.
// Output viewed as float4: each image spans 512 rows * 256 float4 = 1<<17 elements.
// grid.x = 128*8, block = 256: bid>>3 = image, bid&7 = 64-row chunk.
// Each thread reads its float4 of row 0 once, then streams 64 coalesced stores.
__global__ __launch_bounds__(256) void broadcast_kernel(const float4* src, float4* out) {
    const unsigned bid   = blockIdx.x;
    const unsigned img   = bid >> 3;
    const unsigned chunk = bid & 7;
    const unsigned t     = threadIdx.x;

    const size_t base = ((size_t)img << 17);        // img * 512 * 256
    const float4 v = src[base + t];                 // row 0 value (written by kernel A)

    unsigned p0 = chunk * 64;
    if (chunk == 0) p0 = 1;                         // don't rewrite row 0 (aliasing)
    const unsigned p1 = chunk * 64 + 64;

    for (unsigned p = p0; p < p1; ++p) {
        out[base + ((size_t)p << 8) + t] = v;       // 256 float4 per row, fully coalesced
    }
}

extern "C" void kernel_launch(void* const* d_in, const int* in_sizes, int n_in,
                              void* d_out, int out_size, void* d_ws, size_t ws_size,
                              hipStream_t stream) {
    const int*   preds = (const int*)d_in[0];   // pair_preds [128,512] int32
    const float* W     = (const float*)d_in[1]; // [1024,150] fp32
    const float* bias  = (const float*)d_in[2]; // [1024] fp32
    float*       out   = (float*)d_out;         // [65536,1024] fp32

    compute_y_kernel<<<dim3(NB * 4), dim3(256), 0, stream>>>(preds, W, bias, out);
    broadcast_kernel<<<dim3(NB * 8), dim3(256), 0, stream>>>((const float4*)out, (float4*)out);
}